// Round 1
// baseline (571.576 us; speedup 1.0000x reference)
//
#include <hip/hip_runtime.h>
#include <math.h>

// Problem constants (derived from reference): F_IN=128, F_H=16, F_OUT=2.
constexpr int F_IN  = 128;
constexpr int F_H   = 16;
constexpr int F_OUT = 2;

// ---- degree over dst (self-loop added analytically later) ----
__global__ void deg_kernel(const int* __restrict__ dst, int E, int* __restrict__ deg) {
    int e = blockIdx.x * blockDim.x + threadIdx.x;
    if (e < E) atomicAdd(&deg[dst[e]], 1);
}

__global__ void dinv_kernel(const int* __restrict__ deg, float* __restrict__ dinv, int N) {
    int i = blockIdx.x * blockDim.x + threadIdx.x;
    if (i < N) dinv[i] = 1.0f / sqrtf((float)(deg[i] + 1));   // +1 = self-loop
}

// ---- h1 = x @ W1   (one thread per node row, W1 staged in LDS) ----
__global__ void gemm1_kernel(const float* __restrict__ x, const float* __restrict__ W1,
                             float* __restrict__ h1, int N) {
    __shared__ float w[F_IN * F_H];   // 8 KB
    for (int t = threadIdx.x; t < F_IN * F_H; t += blockDim.x) w[t] = W1[t];
    __syncthreads();
    int row = blockIdx.x * blockDim.x + threadIdx.x;
    if (row >= N) return;
    float acc[F_H];
#pragma unroll
    for (int j = 0; j < F_H; ++j) acc[j] = 0.0f;
    const float4* xr = (const float4*)(x + (size_t)row * F_IN);
#pragma unroll 4
    for (int k4 = 0; k4 < F_IN / 4; ++k4) {
        float4 v = xr[k4];
        const float* wr = &w[k4 * 4 * F_H];
#pragma unroll
        for (int j = 0; j < F_H; ++j)
            acc[j] += v.x * wr[j] + v.y * wr[F_H + j] + v.z * wr[2 * F_H + j] + v.w * wr[3 * F_H + j];
    }
    float4* hr = (float4*)(h1 + (size_t)row * F_H);
    hr[0] = make_float4(acc[0],  acc[1],  acc[2],  acc[3]);
    hr[1] = make_float4(acc[4],  acc[5],  acc[6],  acc[7]);
    hr[2] = make_float4(acc[8],  acc[9],  acc[10], acc[11]);
    hr[3] = make_float4(acc[12], acc[13], acc[14], acc[15]);
}

// ---- layer-1 aggregation: 16 lanes per edge (lane = feature) ----
__global__ void agg1_kernel(const int* __restrict__ src, const int* __restrict__ dst,
                            const float* __restrict__ dinv, const float* __restrict__ h1,
                            float* __restrict__ agg1, int E) {
    int t = blockIdx.x * blockDim.x + threadIdx.x;
    int e = t >> 4;
    int lane = t & 15;
    if (e >= E) return;
    int s = src[e], d = dst[e];                 // broadcast within wave (same addr x16)
    float nrm = dinv[s] * dinv[d];
    float val = h1[(size_t)s * F_H + lane] * nrm;   // one 64B line per edge, coalesced
    atomicAdd(&agg1[(size_t)d * F_H + lane], val);
}

// ---- fused: self-loop + bias + ReLU, h2 = y1@W2, out init = b2 + h2*dinv^2 ----
__global__ void finalize_kernel(const float* __restrict__ agg1, const float* __restrict__ h1,
                                const float* __restrict__ dinv, const float* __restrict__ b1,
                                const float* __restrict__ W2, const float* __restrict__ b2,
                                float* __restrict__ h2, float* __restrict__ out, int N) {
    int i = blockIdx.x * blockDim.x + threadIdx.x;
    if (i >= N) return;
    float di2 = dinv[i] * dinv[i];
    float a[F_H], hh[F_H];
    const float4* ar = (const float4*)(agg1 + (size_t)i * F_H);
    const float4* hr = (const float4*)(h1 + (size_t)i * F_H);
#pragma unroll
    for (int q = 0; q < 4; ++q) {
        ((float4*)a)[q]  = ar[q];
        ((float4*)hh)[q] = hr[q];
    }
    float o0 = 0.0f, o1 = 0.0f;
#pragma unroll
    for (int j = 0; j < F_H; ++j) {
        float y = fmaxf(a[j] + hh[j] * di2 + b1[j], 0.0f);   // ReLU(agg + selfloop + bias)
        o0 += y * W2[j * F_OUT + 0];
        o1 += y * W2[j * F_OUT + 1];
    }
    ((float2*)(h2 + (size_t)i * F_OUT))[0] = make_float2(o0, o1);
    out[(size_t)i * F_OUT + 0] = b2[0] + o0 * di2;           // layer-2 self-loop + bias
    out[(size_t)i * F_OUT + 1] = b2[1] + o1 * di2;
}

// ---- layer-2 aggregation: 2 lanes per edge ----
__global__ void agg2_kernel(const int* __restrict__ src, const int* __restrict__ dst,
                            const float* __restrict__ dinv, const float* __restrict__ h2,
                            float* __restrict__ out, int E) {
    int t = blockIdx.x * blockDim.x + threadIdx.x;
    int e = t >> 1;
    int c = t & 1;
    if (e >= E) return;
    int s = src[e], d = dst[e];
    float nrm = dinv[s] * dinv[d];
    atomicAdd(&out[(size_t)d * F_OUT + c], h2[(size_t)s * F_OUT + c] * nrm);
}

extern "C" void kernel_launch(void* const* d_in, const int* in_sizes, int n_in,
                              void* d_out, int out_size, void* d_ws, size_t ws_size,
                              hipStream_t stream) {
    const float* x  = (const float*)d_in[0];
    const int*   ei = (const int*)d_in[1];
    const float* W1 = (const float*)d_in[2];
    const float* b1 = (const float*)d_in[3];
    const float* W2 = (const float*)d_in[4];
    const float* b2 = (const float*)d_in[5];
    float* out = (float*)d_out;

    const int N = out_size / F_OUT;      // 100000
    const int E = in_sizes[1] / 2;       // 3200000
    const int* srcp = ei;
    const int* dstp = ei + E;

    // workspace layout (floats): deg[N] | dinv[N] | h1[16N] | agg1[16N] | h2[2N]
    char* ws = (char*)d_ws;
    int*   deg  = (int*)ws;
    float* dinv = (float*)(ws + (size_t)N * 4);
    float* h1   = (float*)(ws + (size_t)N * 4 * 2);
    float* agg1 = (float*)(ws + (size_t)N * 4 * (2 + F_H));
    float* h2   = (float*)(ws + (size_t)N * 4 * (2 + 2 * F_H));

    hipMemsetAsync(deg, 0, (size_t)N * sizeof(int), stream);
    hipMemsetAsync(agg1, 0, (size_t)N * F_H * sizeof(float), stream);

    deg_kernel<<<(E + 255) / 256, 256, 0, stream>>>(dstp, E, deg);
    dinv_kernel<<<(N + 255) / 256, 256, 0, stream>>>(deg, dinv, N);
    gemm1_kernel<<<(N + 255) / 256, 256, 0, stream>>>(x, W1, h1, N);
    agg1_kernel<<<(E * 16 + 255) / 256, 256, 0, stream>>>(srcp, dstp, dinv, h1, agg1, E);
    finalize_kernel<<<(N + 255) / 256, 256, 0, stream>>>(agg1, h1, dinv, b1, W2, b2, h2, out, N);
    agg2_kernel<<<(E * 2 + 255) / 256, 256, 0, stream>>>(srcp, dstp, dinv, h2, out, E);
}